// Round 8
// baseline (202.004 us; speedup 1.0000x reference)
//
#include <hip/hip_runtime.h>
#include <hip/hip_bf16.h>

typedef __bf16 bf16_t;
typedef __bf16 bf16x8 __attribute__((ext_vector_type(8)));
typedef float f32x4 __attribute__((ext_vector_type(4)));

#define NB 1024
#define ND 32
#define VD 64
#define NH 256
#define NK 2048

// workspace layout (bytes)
#define OFF_A    0                       // 1024*2048 bf16 = 4 MB
#define OFF_W1T  (4u*1024u*1024u)        // 32*256*2048 bf16 = 32 MB
#define OFF_W2T  (36u*1024u*1024u)       // 32*64*256 bf16 = 1 MB

#define MFMA16(AF, BF, ACC) __builtin_amdgcn_mfma_f32_16x16x32_bf16(AF, BF, ACC, 0, 0, 0)

// ---------------- prep (unchanged) ----------------
__global__ __launch_bounds__(256) void prep_kernel(
    const float* __restrict__ cv, const float* __restrict__ adj,
    const float* __restrict__ W1, const float* __restrict__ W2,
    bf16_t* __restrict__ A, bf16_t* __restrict__ W1T, bf16_t* __restrict__ W2T)
{
  __shared__ float Ls[64 * 67];
  int bx = blockIdx.x;
  int tid = threadIdx.x;
  if (bx < 4096) {
    int i = bx >> 7;
    int rem = bx & 127;
    int k0 = (rem >> 2) * 64;
    int h0 = (rem & 3) * 64;
    float a = adj[i * 32 + (k0 >> 6)];
    int rrow = tid >> 4, c4 = (tid & 15) * 4;
#pragma unroll
    for (int p = 0; p < 4; ++p) {
      int row = p * 16 + rrow;
      const float* src = W1 + ((size_t)(i * 2048 + k0 + row)) * 256 + h0 + c4;
      float4 v = *(const float4*)src;
#pragma unroll
      for (int j = 0; j < 4; ++j) Ls[row * 67 + c4 + j] = a * ((const float*)&v)[j];
    }
    __syncthreads();
#pragma unroll
    for (int p = 0; p < 2; ++p) {
      int u = p * 256 + tid;
      int h = u >> 3, c8 = u & 7;
      bf16x8 o;
#pragma unroll
      for (int j = 0; j < 8; ++j) o[j] = (bf16_t)Ls[(c8 * 8 + j) * 67 + h];
      *(bf16x8*)(W1T + ((size_t)(i * 256 + h0 + h)) * 2048 + k0 + c8 * 8) = o;
    }
  } else if (bx < 5120) {
    int t = (bx - 4096) * 256 + tid;
    const float4* s = (const float4*)cv + (size_t)t * 2;
    float4 v0 = s[0], v1 = s[1];
    bf16x8 o;
    o[0] = (bf16_t)v0.x; o[1] = (bf16_t)v0.y; o[2] = (bf16_t)v0.z; o[3] = (bf16_t)v0.w;
    o[4] = (bf16_t)v1.x; o[5] = (bf16_t)v1.y; o[6] = (bf16_t)v1.z; o[7] = (bf16_t)v1.w;
    *(bf16x8*)(A + (size_t)t * 8) = o;
  } else {
    int t = (bx - 5120) * 256 + tid;
    int i = t >> 11;
    int rem = t & 2047;
    int h8 = rem >> 6;
    int v = rem & 63;
    const float* src = W2 + ((size_t)(i * 256 + h8 * 8)) * 64 + v;
    bf16x8 o;
#pragma unroll
    for (int r = 0; r < 8; ++r) o[r] = (bf16_t)src[(size_t)r * 64];
    *(bf16x8*)(W2T + ((size_t)(i * 64 + v)) * 256 + h8 * 8) = o;
  }
}

// ------- fused main: 512 blocks x 512 thr, 64x256 tile, NO LDS staging ------
// A and B fragments read directly global->VGPR (L2/L1-resident working set);
// no barriers in the K-loop; latency hidden by 16 waves/CU TLP.
__global__ __launch_bounds__(512, 4) void sem_main_kernel(
    const bf16_t* __restrict__ A, const bf16_t* __restrict__ W1T,
    const bf16_t* __restrict__ W2T,
    const float* __restrict__ b1, const float* __restrict__ b2,
    const float* __restrict__ gamma, const float* __restrict__ beta,
    float* __restrict__ out)
{
  __shared__ char smem[33792];   // Hs [64][264] bf16 (epilogue only)

  // XCD swizzle: 64 consecutive logical blocks (4 groups x 16 M-blocks) per XCD;
  // neighbor blocks share i -> co-resident blocks likely share the B panel in L1/L2
  int p = blockIdx.x;
  int L = (p & 7) * 64 + (p >> 3);
  int i = L >> 4;          // group 0..31
  int brow = (L & 15) * 64;

  int tid = threadIdx.x;
  int lane = tid & 63;
  int wid = tid >> 6;      // 0..7
  int wr = wid >> 2;       // 0..1  row half (32 rows)
  int wc = wid & 3;        // 0..3  col quarter (64 cols)
  int lhi = lane >> 4;     // 0..3
  int llo = lane & 15;

  const bf16_t* W1Ti = W1T + (size_t)i * 256 * 2048;

  // per-lane fragment base pointers (16B contiguous per lane; 16 rows/frag, stride 4KB)
  const bf16_t* aP = A + (size_t)(brow + wr * 32 + llo) * 2048 + lhi * 8;
  const bf16_t* bP = W1Ti + (size_t)(wc * 64 + llo) * 2048 + lhi * 8;

  f32x4 acc[2][4];
#pragma unroll
  for (int m = 0; m < 2; ++m)
#pragma unroll
    for (int n = 0; n < 4; ++n) acc[m][n] = (f32x4){0.f, 0.f, 0.f, 0.f};

#pragma unroll 4
  for (int kt = 0; kt < 64; ++kt) {
    const bf16_t* ak = aP + kt * 32;
    const bf16_t* bk = bP + kt * 32;
    bf16x8 af0 = *(const bf16x8*)(ak);
    bf16x8 af1 = *(const bf16x8*)(ak + 16 * 2048);
    bf16x8 bf0 = *(const bf16x8*)(bk);
    bf16x8 bf1 = *(const bf16x8*)(bk + 16 * 2048);
    bf16x8 bf2 = *(const bf16x8*)(bk + 32 * 2048);
    bf16x8 bf3 = *(const bf16x8*)(bk + 48 * 2048);
    acc[0][0] = MFMA16(af0, bf0, acc[0][0]);
    acc[0][1] = MFMA16(af0, bf1, acc[0][1]);
    acc[0][2] = MFMA16(af0, bf2, acc[0][2]);
    acc[0][3] = MFMA16(af0, bf3, acc[0][3]);
    acc[1][0] = MFMA16(af1, bf0, acc[1][0]);
    acc[1][1] = MFMA16(af1, bf1, acc[1][1]);
    acc[1][2] = MFMA16(af1, bf2, acc[1][2]);
    acc[1][3] = MFMA16(af1, bf3, acc[1][3]);
  }

  // ---- epilogue 1: bias + exact gelu -> Hs [64][264] bf16 ----
  bf16_t* Hs = (bf16_t*)smem;
  float bias[4];
#pragma unroll
  for (int n = 0; n < 4; ++n) bias[n] = b1[i * 256 + wc * 64 + n * 16 + llo];
#pragma unroll
  for (int m = 0; m < 2; ++m) {
#pragma unroll
    for (int n = 0; n < 4; ++n) {
      int col = wc * 64 + n * 16 + llo;
#pragma unroll
      for (int r = 0; r < 4; ++r) {
        int row = wr * 32 + m * 16 + lhi * 4 + r;   // D: row=(lane>>4)*4+reg, col=lane&15
        float x = acc[m][n][r] + bias[n];
        float gl = 0.5f * x * (1.0f + erff(x * 0.70710678118654752f));
        Hs[row * 264 + col] = (bf16_t)gl;
      }
    }
  }
  __syncthreads();

  // ---- GEMM2 + LN: waves 0-3 handle 16 rows each ----
  if (wid < 4) {
    f32x4 acc2[4];
#pragma unroll
    for (int n = 0; n < 4; ++n) acc2[n] = (f32x4){0.f, 0.f, 0.f, 0.f};
    const bf16_t* W2Ti = W2T + (size_t)i * 64 * 256;
#pragma unroll
    for (int kk = 0; kk < 8; ++kk) {
      int k = kk * 32 + lhi * 8;
      bf16x8 af = *(const bf16x8*)(Hs + (wid * 16 + llo) * 264 + k);
#pragma unroll
      for (int n = 0; n < 4; ++n) {
        bf16x8 bfr = *(const bf16x8*)(W2Ti + (size_t)(n * 16 + llo) * 256 + k);
        acc2[n] = MFMA16(af, bfr, acc2[n]);
      }
    }
    float b2v[4], gam[4], bet[4];
#pragma unroll
    for (int n = 0; n < 4; ++n) {
      int v = n * 16 + llo;
      b2v[n] = b2[i * 64 + v];
      gam[n] = gamma[i * 64 + v];
      bet[n] = beta[i * 64 + v];
    }
#pragma unroll
    for (int r = 0; r < 4; ++r) {
      float yv[4], s = 0.f, sq = 0.f;
#pragma unroll
      for (int n = 0; n < 4; ++n) {
        yv[n] = acc2[n][r] + b2v[n];
        s += yv[n];
        sq += yv[n] * yv[n];
      }
#pragma unroll
      for (int off = 1; off < 16; off <<= 1) {
        s += __shfl_xor(s, off, 64);
        sq += __shfl_xor(sq, off, 64);
      }
      float mu = s * (1.0f / 64.0f);
      float var = sq * (1.0f / 64.0f) - mu * mu;
      float rstd = rsqrtf(var + 1e-5f);
      int row = brow + wid * 16 + lhi * 4 + r;
      float* op = out + ((size_t)row * 32 + i) * 64;
#pragma unroll
      for (int n = 0; n < 4; ++n)
        op[n * 16 + llo] = (yv[n] - mu) * rstd * gam[n] + bet[n];
    }
  }
}

extern "C" void kernel_launch(void* const* d_in, const int* in_sizes, int n_in,
                              void* d_out, int out_size, void* d_ws, size_t ws_size,
                              hipStream_t stream) {
  const float* cv    = (const float*)d_in[0];
  const float* adj   = (const float*)d_in[1];
  const float* W1    = (const float*)d_in[2];
  const float* b1    = (const float*)d_in[3];
  const float* W2    = (const float*)d_in[4];
  const float* b2    = (const float*)d_in[5];
  const float* gamma = (const float*)d_in[6];
  const float* beta  = (const float*)d_in[7];
  float* out = (float*)d_out;

  bf16_t* Abf  = (bf16_t*)((char*)d_ws + OFF_A);
  bf16_t* W1T  = (bf16_t*)((char*)d_ws + OFF_W1T);
  bf16_t* W2T  = (bf16_t*)((char*)d_ws + OFF_W2T);

  prep_kernel<<<5376, 256, 0, stream>>>(cv, adj, W1, W2, Abf, W1T, W2T);
  sem_main_kernel<<<512, 512, 0, stream>>>(Abf, W1T, W2T, b1, b2, gamma, beta, out);
}

// Round 9
// 70.775 us; speedup vs baseline: 2.8542x; 2.8542x over previous
//
#include <hip/hip_runtime.h>
#include <hip/hip_bf16.h>

typedef __bf16 bf16_t;
typedef __bf16 bf16x8 __attribute__((ext_vector_type(8)));
typedef float f32x4 __attribute__((ext_vector_type(4)));

#define NB 1024
#define ND 32
#define VD 64
#define NH 256
#define NK 2048

// workspace layout (bytes)
#define OFF_A    0                       // 1024*2048 bf16 = 4 MB
#define OFF_W1T  (4u*1024u*1024u)        // 32*256*2048 bf16 = 32 MB
#define OFF_W2T  (36u*1024u*1024u)       // 32*64*256 bf16 = 1 MB

#define GLD16(gsrc, ldst) \
  __builtin_amdgcn_global_load_lds((const __attribute__((address_space(1))) void*)(gsrc), \
                                   (__attribute__((address_space(3))) void*)(ldst), 16, 0, 0)

// ---------------- prep (unchanged) ----------------
__global__ __launch_bounds__(256) void prep_kernel(
    const float* __restrict__ cv, const float* __restrict__ adj,
    const float* __restrict__ W1, const float* __restrict__ W2,
    bf16_t* __restrict__ A, bf16_t* __restrict__ W1T, bf16_t* __restrict__ W2T)
{
  __shared__ float Ls[64 * 67];
  int bx = blockIdx.x;
  int tid = threadIdx.x;
  if (bx < 4096) {
    int i = bx >> 7;
    int rem = bx & 127;
    int k0 = (rem >> 2) * 64;
    int h0 = (rem & 3) * 64;
    float a = adj[i * 32 + (k0 >> 6)];
    int rrow = tid >> 4, c4 = (tid & 15) * 4;
#pragma unroll
    for (int p = 0; p < 4; ++p) {
      int row = p * 16 + rrow;
      const float* src = W1 + ((size_t)(i * 2048 + k0 + row)) * 256 + h0 + c4;
      float4 v = *(const float4*)src;
#pragma unroll
      for (int j = 0; j < 4; ++j) Ls[row * 67 + c4 + j] = a * ((const float*)&v)[j];
    }
    __syncthreads();
#pragma unroll
    for (int p = 0; p < 2; ++p) {
      int u = p * 256 + tid;
      int h = u >> 3, c8 = u & 7;
      bf16x8 o;
#pragma unroll
      for (int j = 0; j < 8; ++j) o[j] = (bf16_t)Ls[(c8 * 8 + j) * 67 + h];
      *(bf16x8*)(W1T + ((size_t)(i * 256 + h0 + h)) * 2048 + k0 + c8 * 8) = o;
    }
  } else if (bx < 5120) {
    int t = (bx - 4096) * 256 + tid;
    const float4* s = (const float4*)cv + (size_t)t * 2;
    float4 v0 = s[0], v1 = s[1];
    bf16x8 o;
    o[0] = (bf16_t)v0.x; o[1] = (bf16_t)v0.y; o[2] = (bf16_t)v0.z; o[3] = (bf16_t)v0.w;
    o[4] = (bf16_t)v1.x; o[5] = (bf16_t)v1.y; o[6] = (bf16_t)v1.z; o[7] = (bf16_t)v1.w;
    *(bf16x8*)(A + (size_t)t * 8) = o;
  } else {
    int t = (bx - 5120) * 256 + tid;
    int i = t >> 11;
    int rem = t & 2047;
    int h8 = rem >> 6;
    int v = rem & 63;
    const float* src = W2 + ((size_t)(i * 256 + h8 * 8)) * 64 + v;
    bf16x8 o;
#pragma unroll
    for (int r = 0; r < 8; ++r) o[r] = (bf16_t)src[(size_t)r * 64];
    *(bf16x8*)(W2T + ((size_t)(i * 64 + v)) * 256 + h8 * 8) = o;
  }
}

// ------ fused main: 256 blocks x 1024 thr (16 waves), 128x256 tile, BK=32, depth-3 pipeline ----
__global__ __launch_bounds__(1024, 4) void sem_main_kernel(
    const bf16_t* __restrict__ A, const bf16_t* __restrict__ W1T,
    const bf16_t* __restrict__ W2T,
    const float* __restrict__ b1, const float* __restrict__ b2,
    const float* __restrict__ gamma, const float* __restrict__ beta,
    float* __restrict__ out)
{
  __shared__ char smem[73728];   // 3 x (A 8KB + B 16KB) = 72KB; epilogue Hs [128][264] = 67.6KB

  // XCD swizzle: 32 consecutive logical blocks (4 groups x 8 M-blocks) per XCD
  int p = blockIdx.x;
  int L = (p & 7) * 32 + (p >> 3);
  int i = L >> 3;           // group 0..31
  int brow = (L & 7) * 128; // M-block row

  int tid = threadIdx.x;
  int lane = tid & 63;
  int wid = tid >> 6;       // 0..15
  int wr = wid >> 2;        // 0..3  row quarter (32 rows)
  int wc = wid & 3;         // 0..3  col quarter (64 cols)
  int lhi = lane >> 4;      // 0..3
  int llo = lane & 15;

  const bf16_t* W1Ti = W1T + (size_t)i * 256 * 2048;

  // staging sources (pre-swizzled, G21): row = tid>>2, chunk = tid&3; sc = c ^ ((row>>1)&3)
  int srow = tid >> 2, sc4 = tid & 3;
  int scz = sc4 ^ ((srow >> 1) & 3);
  const bf16_t* bSrc = W1Ti + (size_t)srow * 2048 + scz * 8;              // rows 0..255 (all threads)
  const bf16_t* aSrc = A + (size_t)(brow + srow) * 2048 + scz * 8;        // rows 0..127 (tid<512)
  int ldsW = wid * 1024;    // wave-uniform LDS dest (lane*16 implicit)

  // stage tile kt into buffer b: waves 0-7 stage A (8KB) + B half; waves 8-15 stage B half
  auto stage = [&](int b, int kt) {
    char* base = smem + b * 24576;
    if (wid < 8) GLD16(aSrc + (size_t)kt * 32, base + ldsW);
    GLD16(bSrc + (size_t)kt * 32, base + 8192 + ldsW);
  };

  // fragment LDS byte offsets (swizzled reads): A [128][32] at 0, B [256][32] at +8192
  int aOff[2], bOff[4];
#pragma unroll
  for (int m = 0; m < 2; ++m) {
    int row = wr * 32 + m * 16 + llo;
    aOff[m] = row * 64 + ((lhi ^ ((row >> 1) & 3)) * 16);
  }
#pragma unroll
  for (int n = 0; n < 4; ++n) {
    int row = wc * 64 + n * 16 + llo;
    bOff[n] = 8192 + row * 64 + ((lhi ^ ((row >> 1) & 3)) * 16);
  }

  f32x4 acc[2][4];
#pragma unroll
  for (int m = 0; m < 2; ++m)
#pragma unroll
    for (int n = 0; n < 4; ++n) acc[m][n] = (f32x4){0.f, 0.f, 0.f, 0.f};

  auto compute = [&](int b) {
    const char* base = smem + b * 24576;
    bf16x8 af[2], bfr[4];
#pragma unroll
    for (int m = 0; m < 2; ++m) af[m] = *(const bf16x8*)(base + aOff[m]);
#pragma unroll
    for (int n = 0; n < 4; ++n) bfr[n] = *(const bf16x8*)(base + bOff[n]);
    __builtin_amdgcn_s_setprio(1);
#pragma unroll
    for (int m = 0; m < 2; ++m)
#pragma unroll
      for (int n = 0; n < 4; ++n)
        acc[m][n] = __builtin_amdgcn_mfma_f32_16x16x32_bf16(af[m], bfr[n], acc[m][n], 0, 0, 0);
    __builtin_amdgcn_s_setprio(0);
  };

  // per-wave-class counted waits: waves 0-7 issue 2 loads/tile, waves 8-15 issue 1
#define WAIT_OWN_TILE() do { \
    if (wid < 8) asm volatile("s_waitcnt vmcnt(2) lgkmcnt(0)" ::: "memory"); \
    else         asm volatile("s_waitcnt vmcnt(1) lgkmcnt(0)" ::: "memory"); \
  } while (0)

  asm volatile("" ::: "memory");
  stage(0, 0); stage(1, 1);
  int bc = 0, bs = 2;
  for (int t = 0; t < 62; ++t) {
    WAIT_OWN_TILE();                       // own tile-t loads landed (t+1 still in flight)
    __builtin_amdgcn_s_barrier();          // all waves' tile-t landed; tile t-1 reads done
    asm volatile("" ::: "memory");
    stage(bs, t + 2);
    compute(bc);
    bc = (bc == 2) ? 0 : bc + 1;
    bs = (bs == 2) ? 0 : bs + 1;
  }
  WAIT_OWN_TILE();
  __builtin_amdgcn_s_barrier();
  asm volatile("" ::: "memory");
  compute(2);                              // tile 62 (62 mod 3 == 2)
  asm volatile("s_waitcnt vmcnt(0) lgkmcnt(0)" ::: "memory");
  __builtin_amdgcn_s_barrier();
  asm volatile("" ::: "memory");
  compute(0);                              // tile 63 (63 mod 3 == 0)
  __syncthreads();                         // drain before smem reuse

  // ---- epilogue 1: bias + exact gelu -> Hs [128][264] bf16 ----
  bf16_t* Hs = (bf16_t*)smem;
  float bias[4];
#pragma unroll
  for (int n = 0; n < 4; ++n) bias[n] = b1[i * 256 + wc * 64 + n * 16 + llo];
#pragma unroll
  for (int m = 0; m < 2; ++m) {
#pragma unroll
    for (int n = 0; n < 4; ++n) {
      int col = wc * 64 + n * 16 + llo;
#pragma unroll
      for (int r = 0; r < 4; ++r) {
        int row = wr * 32 + m * 16 + lhi * 4 + r;   // D: row=(lane>>4)*4+reg, col=lane&15
        float x = acc[m][n][r] + bias[n];
        float gl = 0.5f * x * (1.0f + erff(x * 0.70710678118654752f));
        Hs[row * 264 + col] = (bf16_t)gl;
      }
    }
  }
  __syncthreads();

  // ---- GEMM2 + LN: waves 0-7 handle 16 rows each ----
  if (wid < 8) {
    f32x4 acc2[4];
#pragma unroll
    for (int n = 0; n < 4; ++n) acc2[n] = (f32x4){0.f, 0.f, 0.f, 0.f};
    const bf16_t* W2Ti = W2T + (size_t)i * 64 * 256;
#pragma unroll
    for (int kk = 0; kk < 8; ++kk) {
      int k = kk * 32 + lhi * 8;
      bf16x8 af = *(const bf16x8*)(Hs + (wid * 16 + llo) * 264 + k);
#pragma unroll
      for (int n = 0; n < 4; ++n) {
        bf16x8 bfr = *(const bf16x8*)(W2Ti + (size_t)(n * 16 + llo) * 256 + k);
        acc2[n] = __builtin_amdgcn_mfma_f32_16x16x32_bf16(af, bfr, acc2[n], 0, 0, 0);
      }
    }
    float b2v[4], gam[4], bet[4];
#pragma unroll
    for (int n = 0; n < 4; ++n) {
      int v = n * 16 + llo;
      b2v[n] = b2[i * 64 + v];
      gam[n] = gamma[i * 64 + v];
      bet[n] = beta[i * 64 + v];
    }
#pragma unroll
    for (int r = 0; r < 4; ++r) {
      float yv[4], s = 0.f, sq = 0.f;
#pragma unroll
      for (int n = 0; n < 4; ++n) {
        yv[n] = acc2[n][r] + b2v[n];
        s += yv[n];
        sq += yv[n] * yv[n];
      }
#pragma unroll
      for (int off = 1; off < 16; off <<= 1) {
        s += __shfl_xor(s, off, 64);
        sq += __shfl_xor(sq, off, 64);
      }
      float mu = s * (1.0f / 64.0f);
      float var = sq * (1.0f / 64.0f) - mu * mu;
      float rstd = rsqrtf(var + 1e-5f);
      int row = brow + wid * 16 + lhi * 4 + r;
      float* op = out + ((size_t)row * 32 + i) * 64;
#pragma unroll
      for (int n = 0; n < 4; ++n)
        op[n * 16 + llo] = (yv[n] - mu) * rstd * gam[n] + bet[n];
    }
  }
}

extern "C" void kernel_launch(void* const* d_in, const int* in_sizes, int n_in,
                              void* d_out, int out_size, void* d_ws, size_t ws_size,
                              hipStream_t stream) {
  const float* cv    = (const float*)d_in[0];
  const float* adj   = (const float*)d_in[1];
  const float* W1    = (const float*)d_in[2];
  const float* b1    = (const float*)d_in[3];
  const float* W2    = (const float*)d_in[4];
  const float* b2    = (const float*)d_in[5];
  const float* gamma = (const float*)d_in[6];
  const float* beta  = (const float*)d_in[7];
  float* out = (float*)d_out;

  bf16_t* Abf  = (bf16_t*)((char*)d_ws + OFF_A);
  bf16_t* W1T  = (bf16_t*)((char*)d_ws + OFF_W1T);
  bf16_t* W2T  = (bf16_t*)((char*)d_ws + OFF_W2T);

  prep_kernel<<<5376, 256, 0, stream>>>(cv, adj, W1, W2, Abf, W1T, W2T);
  sem_main_kernel<<<256, 1024, 0, stream>>>(Abf, W1T, W2T, b1, b2, gamma, beta, out);
}